// Round 10
// baseline (131.474 us; speedup 1.0000x reference)
//
#include <hip/hip_runtime.h>
#include <math.h>

#define BSZ    8192
#define DDIM   256
#define SCALE  33.33333333333333f   // 1/0.03
#define C_OFF  34.0f                // fixed LSE offset: |sim*SCALE| <= 33.34
#define SC_L2E 48.08983470f         // SCALE * log2(e)
#define C2     49.05163139f         // C_OFF * log2(e)

typedef float floatx4  __attribute__((ext_vector_type(4)));
typedef float floatx16 __attribute__((ext_vector_type(16)));
typedef int   intx4    __attribute__((ext_vector_type(4)));
typedef int   intx8    __attribute__((ext_vector_type(8)));
typedef long long fp8x8;            // 8 x fp8 e4m3

// pack 8 fp32 -> 8 fp8 e4m3 (HW cvt; format matches the fp8 MFMA operand)
__device__ __forceinline__ fp8x8 cvt8_f8(const float* __restrict__ g)
{
    const float4 lo = *(const float4*)g;
    const float4 hi = *(const float4*)(g + 4);
    int a = __builtin_amdgcn_cvt_pk_fp8_f32(lo.x, lo.y, 0, false);
    a     = __builtin_amdgcn_cvt_pk_fp8_f32(lo.z, lo.w, a, true);
    int b = __builtin_amdgcn_cvt_pk_fp8_f32(hi.x, hi.y, 0, false);
    b     = __builtin_amdgcn_cvt_pk_fp8_f32(hi.z, hi.w, b, true);
    int2 r; r.x = a; r.y = b;
    return *(fp8x8*)&r;
}

// ---------------------------------------------------------------- prep
// za_f8: row-major [8192][256] fp8.
// zt_perm layout: byte(cb,col,gph,off) = cb*32768 + col*256 + gph*16 + off;
// physical granule gph holds LOGICAL k-granule kg = gph ^ (col&15).
// Also zeroes s_row/s_col and the 4 control words (total, flag, cnt1, cnt2).
__global__ __launch_bounds__(256) void prep_kernel(
    const float* __restrict__ za, const float* __restrict__ zt,
    unsigned char* __restrict__ za_f8, unsigned char* __restrict__ zt_perm,
    float* __restrict__ zbase)
{
    const int bid = blockIdx.x, tid = threadIdx.x;
    if (bid < 1024) {
        const int i = (bid * 256 + tid) * 8;
        *(fp8x8*)(za_f8 + i) = cvt8_f8(za + i);
        if (bid < 16) {
            const int z = bid * 1024 + tid * 4;
            *(float4*)&zbase[z] = (float4){0.f, 0.f, 0.f, 0.f};
            if (bid == 0 && tid == 0) {
                zbase[16384] = 0.f;          // total
                ((int*)zbase)[16385] = 0;    // flag
                ((int*)zbase)[16386] = 0;    // cnt1 (grid barrier)
                ((int*)zbase)[16387] = 0;    // cnt2 (finalize fan-in)
            }
        }
    } else {
        const int S    = (bid - 1024) * 256 + tid;   // global 8-B slot id
        const int cbb  = S >> 12;                    // col-block 0..63
        const int col  = (S >> 5) & 127;             // col within block
        const int gph  = (S >> 1) & 15;              // physical 16B granule
        const int off8 = (S & 1) * 8;
        const int k    = ((gph ^ (col & 15)) << 4) + off8;  // logical k byte
        const float* src = zt + (size_t)(cbb * 128 + col) * DDIM + k;
        *(fp8x8*)(zt_perm + (size_t)S * 8) = cvt8_f8(src);
    }
}

// ---------------------------------------------------------------- sim (+fused finalize)
// ROUND-10: R8's best-measured body (512 blocks, 8 tiles, B pinned in LDS,
// zero K-loop syncs) + finalize FUSED via a software grid barrier.
// R9 post-mortem: fill(43us, harness poison, uncontrollable) + sim(~34) +
// prep(~10) + finalize+gap(~10) + launches ~ 102. Occupancy 2x (R9) = null
// -> TLP exonerated. Biggest controllable term after sim: the finalize
// launch + inter-kernel drain gap. Fusion design (DEADLOCK-FREE):
//  - every block: work -> threadfence -> atomicAdd(cnt1) -> blocks>=32 EXIT
//  - only blocks 0..31 spin (cnt1==512); nobody waits on a waiter -> safe
//    at ANY occupancy. They then do the finalize rows (256 each).
//  - cross-XCD visibility (G16): s_row/s_col accumulated by device-scope
//    atomicAdd; posv written by atomicExch; finalize READS via atomic RMW
//    (no reliance on kernel-boundary cache flush).
//  - last of the 32 (cnt2) writes out[0] (old finalize tail).
// Micro: B operand assembled by writing both ds_read_b128 results into the
// intx8 halves directly (no element-wise repack).
// Tripwires: VGPR<=128 (launch_bounds cap), FETCH ~9.9MB, absmax 0.
__global__ __launch_bounds__(256, 2) void sim_fused(
    const unsigned char* __restrict__ za_f8, const unsigned char* __restrict__ zt_perm,
    const int* __restrict__ pid,
    float* __restrict__ s_row, float* __restrict__ s_col,
    float* __restrict__ posv,
    float* __restrict__ total, int* __restrict__ flag,
    int* __restrict__ cnt1, int* __restrict__ cnt2,
    float* __restrict__ out)
{
    __shared__ __align__(16) unsigned char Bs[32768];   // 128 cols x 256 k fp8
    __shared__ int   pidc[128];
    __shared__ float colsum[128];

    const int bid   = blockIdx.x;
    const int cbb   = bid & 63;          // column block (fixed for this block)
    const int bgrp  = bid >> 6;          // 0..7 -> bands bgrp*8 .. bgrp*8+7
    const int col0g = cbb * 128;
    const int tid   = threadIdx.x, lane = tid & 63, wid = tid >> 6;
    const int l31   = lane & 31, h = lane >> 5;

    if (tid < 128) { pidc[tid] = pid[col0g + tid]; colsum[tid] = 0.f; }

    // ---- stage B once: 32KB, 4 waves x 8KB, width-16 global_load_lds
    {
        const unsigned char* src = zt_perm + (size_t)cbb * 32768 + wid * 8192 + lane * 16;
        unsigned char* dst = Bs + wid * 8192 + lane * 16;
        #pragma unroll
        for (int i = 0; i < 8; i++)
            __builtin_amdgcn_global_load_lds(
                (const __attribute__((address_space(1))) void*)(src + i * 1024),
                (__attribute__((address_space(3))) void*)(dst + i * 1024),
                16, 0, 0);
    }

    // ---- tile-0 A fragments (prefetch while staging is in flight)
    const int band0 = bgrp * 8;
    intx8 afc[4];
    {
        const unsigned char* ga =
            za_f8 + (size_t)(band0 * 128 + wid * 32 + l31) * DDIM + h * 32;
        #pragma unroll
        for (int ks = 0; ks < 4; ks++)
            afc[ks] = *(const intx8*)(ga + ks * 64);
    }

    __syncthreads();   // B + pidc visible. ONLY barrier until the final flush.

    // ds_read bases for B (fixed across all 8 tiles)
    const int t16 = ((((lane >> 4) & 2) ^ (lane & 15)) << 4);  // ((2h)^s)<<4
    int dsb[4];
    #pragma unroll
    for (int n = 0; n < 4; n++)
        dsb[n] = n * 8192 + l31 * 256 + t16;

    // col pids (tile-invariant)
    int pc[4];
    #pragma unroll
    for (int n = 0; n < 4; n++) pc[n] = pidc[n * 32 + l31];

    float colp4[4] = {0.f, 0.f, 0.f, 0.f};   // accumulates across ALL 8 tiles
    const int  target = (lane & 3) + 4 * ((lane >> 3) & 3);  // reg holding diag
    const bool ownl   = (h == ((lane >> 2) & 1));            // h matches row bit2

    #pragma unroll
    for (int i = 0; i < 8; i++) {
        const int band  = band0 + i;
        const int rbase = band * 128 + wid * 32;

        // prefetch NEXT tile's A (issued before MFMAs -> latency hidden)
        intx8 afn[4];
        if (i < 7) {
            const unsigned char* ga =
                za_f8 + (size_t)(rbase + 128 + l31) * DDIM + h * 32;
            #pragma unroll
            for (int ks = 0; ks < 4; ks++)
                afn[ks] = *(const intx8*)(ga + ks * 64);
        }

        // row pids for this tile (used only in epilogue -> load covered by MFMAs)
        int prw[16];
        #pragma unroll
        for (int reg = 0; reg < 16; reg++)
            prw[reg] = pid[rbase + (reg & 3) + 8 * (reg >> 2) + 4 * h];

        // ---- GEMM: 32 ds_read_b128 + 16 mfma_scale
        floatx16 acc[4];
        #pragma unroll
        for (int n = 0; n < 4; n++) acc[n] = (floatx16)0.0f;

        #pragma unroll
        for (int ks = 0; ks < 4; ks++) {
            #pragma unroll
            for (int n = 0; n < 4; n++) {
                intx8 b;
                *(intx4*)&b =
                    *(const intx4*)(Bs + (dsb[n] ^ ((ks * 4 + 0) << 4)));
                *(((intx4*)&b) + 1) =
                    *(const intx4*)(Bs + (dsb[n] ^ ((ks * 4 + 1) << 4)));
                acc[n] = __builtin_amdgcn_mfma_scale_f32_32x32x64_f8f6f4(
                    afc[ks], b, acc[n], 0, 0, 0, 0x7F7F7F7F, 0, 0x7F7F7F7F);
            }
        }

        // ---- epilogue (wave-local, no syncs)
        float rowp[16];
        #pragma unroll
        for (int r = 0; r < 16; r++) rowp[r] = 0.f;

        #pragma unroll
        for (int n = 0; n < 4; n++) {
            const int pcn = pc[n];
            #pragma unroll
            for (int reg = 0; reg < 16; reg++) {
                float e = __builtin_amdgcn_exp2f(fmaf(acc[n][reg], SC_L2E, -C2));
                e = (prw[reg] != pcn) ? e : 0.f;
                colp4[n] += e;
                rowp[reg] += e;
            }
            if (band == cbb && n == wid) {   // diagonal fixup (wave-uniform)
                float vd = 0.f;
                #pragma unroll
                for (int reg = 0; reg < 16; reg++)
                    vd = (reg == target) ? acc[n][reg] : vd;   // cndmask chain
                float ed = __builtin_amdgcn_exp2f(fmaf(vd, SC_L2E, -C2));
                ed = ownl ? ed : 0.f;
                colp4[n] += ed;
                #pragma unroll
                for (int reg = 0; reg < 16; reg++)
                    rowp[reg] += (reg == target) ? ed : 0.f;   // ed=0 if !ownl
                if (ownl)   // device-scope write: finalize reads cross-XCD
                    atomicExch(&posv[band * 128 + wid * 32 + l31], vd * SCALE);
            }
        }

        // row sums: split-tree reduce of rowp[16] over the 32-lane half
#define RED(bit, c)                                                        \
        _Pragma("unroll")                                                  \
        for (int _i = 0; _i < (c); _i++) {                                 \
            float _s = (lane & (bit)) ? rowp[_i] : rowp[_i + (c)];         \
            float _o = __shfl_xor(_s, (bit), 64);                          \
            rowp[_i] = ((lane & (bit)) ? rowp[_i + (c)] : rowp[_i]) + _o;  \
        }
        RED(1, 8) RED(2, 4) RED(4, 2) RED(8, 1)
#undef RED
        rowp[0] += __shfl_xor(rowp[0], 16, 64);
        if ((lane & 16) == 0) {
            const int reg = ((lane & 1) << 3) | ((lane & 2) << 1)
                          | ((lane & 4) >> 1) | ((lane & 8) >> 3);
            const int rl  = (reg & 3) + 8 * (reg >> 2) + 4 * h;
            atomicAdd(&s_row[rbase + rl], rowp[0]);
        }

        // rotate pipelined A
        if (i < 7) {
            #pragma unroll
            for (int ks = 0; ks < 4; ks++) afc[ks] = afn[ks];
        }
    }

    // ---- col flush (once per block, after all 8 tiles)
    #pragma unroll
    for (int n = 0; n < 4; n++)
        colp4[n] += __shfl_xor(colp4[n], 32, 64);
    if (lane < 32) {
        #pragma unroll
        for (int n = 0; n < 4; n++)
            atomicAdd(&colsum[n * 32 + lane], colp4[n]);
    }
    __syncthreads();
    if (tid < 128) atomicAdd(&s_col[col0g + tid], colsum[tid]);

    // =========== software grid barrier (deadlock-free: only blocks 0..31 spin)
    __syncthreads();
    __threadfence();                      // release all our global writes
    if (tid == 0) atomicAdd(cnt1, 1);     // arrive
    if (bid >= 32) return;                // non-finalizers exit immediately

    if (tid == 0) {
        while (atomicAdd(cnt1, 0) < 512) { __builtin_amdgcn_s_sleep(8); }
    }
    __syncthreads();                      // whole block sees barrier passed

    // =========== fused finalize: 32 blocks x 256 rows
    {
        const int i = bid * 256 + tid;
        // device-scope atomic reads (cross-XCD coherent; G16)
        const float sr = atomicAdd(&s_row[i], 0.0f);
        const float sc = atomicAdd(&s_col[i], 0.0f);
        const float p  = atomicAdd(&posv[i], 0.0f);
        const float c  = (logf(sr) + C_OFF - p)
                       + (logf(sc) + C_OFF - p);

        float v = c;
        #pragma unroll
        for (int off = 32; off > 0; off >>= 1) v += __shfl_down(v, off, 64);
        if ((tid & 63) == 0) atomicAdd(total, v);

        const unsigned long long m = __ballot(pid[i] != pid[0]);
        if (m != 0ull && (tid & 63) == 0) atomicOr(flag, 1);

        __syncthreads();
        __threadfence();
        if (tid == 0) {
            const int done = atomicAdd(cnt2, 1);
            if (done == 31) {
                const float t = atomicAdd(total, 0.0f);
                const int   f = atomicOr(flag, 0);
                out[0] = f ? t / (2.0f * (float)BSZ) : 0.0f;
            }
        }
    }
}

// ---------------------------------------------------------------- launcher
extern "C" void kernel_launch(void* const* d_in, const int* in_sizes, int n_in,
                              void* d_out, int out_size, void* d_ws, size_t ws_size,
                              hipStream_t stream)
{
    const float* za  = (const float*)d_in[0];
    const float* zt  = (const float*)d_in[1];
    const int*   pid = (const int*)d_in[2];
    float* out = (float*)d_out;

    // ws: za_f8 2MB | zt_perm 2MB | s_row[8192] s_col[8192] total flag cnt1 cnt2 posv[8192]
    unsigned char* za_f8   = (unsigned char*)d_ws;
    unsigned char* zt_perm = za_f8 + (size_t)BSZ * DDIM;
    float*  s_row   = (float*)(zt_perm + (size_t)BSZ * DDIM);
    float*  s_col   = s_row + BSZ;
    float*  total   = s_col + BSZ;
    int*    flag    = (int*)(total + 1);
    int*    cnt1    = flag + 1;
    int*    cnt2    = cnt1 + 1;
    float*  posv    = (float*)(cnt2 + 1);

    prep_kernel<<<dim3(2048), 256, 0, stream>>>(za, zt, za_f8, zt_perm, s_row);

    sim_fused<<<dim3(512), 256, 0, stream>>>(za_f8, zt_perm, pid,
                                             s_row, s_col, posv,
                                             total, flag, cnt1, cnt2, out);
}

// Round 11
// 115.515 us; speedup vs baseline: 1.1382x; 1.1382x over previous
//
#include <hip/hip_runtime.h>
#include <math.h>

#define BSZ    8192
#define DDIM   256
#define SCALE  33.33333333333333f   // 1/0.03
#define C_OFF  34.0f                // fixed LSE offset: |sim*SCALE| <= 33.34
#define SC_L2E 48.08983470f         // SCALE * log2(e)
#define C2     49.05163139f         // C_OFF * log2(e)

typedef float floatx4  __attribute__((ext_vector_type(4)));
typedef float floatx16 __attribute__((ext_vector_type(16)));
typedef int   intx4    __attribute__((ext_vector_type(4)));
typedef int   intx8    __attribute__((ext_vector_type(8)));
typedef long long fp8x8;            // 8 x fp8 e4m3

// pack 8 fp32 -> 8 fp8 e4m3 (HW cvt; format matches the fp8 MFMA operand)
__device__ __forceinline__ fp8x8 cvt8_f8(const float* __restrict__ g)
{
    const float4 lo = *(const float4*)g;
    const float4 hi = *(const float4*)(g + 4);
    int a = __builtin_amdgcn_cvt_pk_fp8_f32(lo.x, lo.y, 0, false);
    a     = __builtin_amdgcn_cvt_pk_fp8_f32(lo.z, lo.w, a, true);
    int b = __builtin_amdgcn_cvt_pk_fp8_f32(hi.x, hi.y, 0, false);
    b     = __builtin_amdgcn_cvt_pk_fp8_f32(hi.z, hi.w, b, true);
    int2 r; r.x = a; r.y = b;
    return *(fp8x8*)&r;
}

// ---------------------------------------------------------------- prep
// za_f8: row-major [8192][256] fp8 (unchanged).
// zt_perm NEW operand-major layout (derived both directions, R6 lesson):
//   byte(cb, o, lane, part) = cb*32768 + o*2048 + lane*32 + part*8
//   where o = ks*4+n. Lane l of operand (ks,n) holds
//   col = cb*128 + n*32 + (l&31), k = ks*64 + (l>>5)*32 + part*8 .. +8.
//   This IS the HW B-operand layout for mfma_scale_32x32x64 (lane = col +
//   32*k_half) -> sim reads one contiguous 32B per lane, fully coalesced
//   (2KB per operand per wave), byte-identical values to R8's LDS path.
__global__ __launch_bounds__(256) void prep_kernel(
    const float* __restrict__ za, const float* __restrict__ zt,
    unsigned char* __restrict__ za_f8, unsigned char* __restrict__ zt_perm,
    float* __restrict__ zbase)
{
    const int bid = blockIdx.x, tid = threadIdx.x;
    if (bid < 1024) {
        const int i = (bid * 256 + tid) * 8;
        *(fp8x8*)(za_f8 + i) = cvt8_f8(za + i);
        if (bid < 16) {
            const int z = bid * 1024 + tid * 4;
            *(float4*)&zbase[z] = (float4){0.f, 0.f, 0.f, 0.f};
            if (bid == 0 && tid == 0) {
                zbase[16384] = 0.f;          // total
                ((int*)zbase)[16385] = 0;    // flag
                ((int*)zbase)[16386] = 0;    // cnt
            }
        }
    } else {
        const int S    = (bid - 1024) * 256 + tid;   // global 8-B slot id
        const int cbb  = S >> 12;                    // col-block 0..63
        const int r    = S & 4095;                   // slot within cb (32KB)
        const int o    = r >> 8;                     // operand 0..15 (2KB each)
        const int w    = r & 255;                    // slot within operand
        const int ln   = w >> 2;                     // lane 0..63
        const int part = w & 3;                      // 8B part 0..3
        const int ks   = o >> 2, n = o & 3;
        const int col  = cbb * 128 + n * 32 + (ln & 31);
        const int k    = ks * 64 + (ln >> 5) * 32 + part * 8;
        const float* src = zt + (size_t)col * DDIM + k;
        *(fp8x8*)(zt_perm + (size_t)S * 8) = cvt8_f8(src);
    }
}

// ---------------------------------------------------------------- sim
// ROUND-11: B ENTIRELY IN REGISTERS. R10's fusion reverted (A/B: 131.5 vs
// R8's 102.0). R8 pipe accounting: LDS co-binds with MFMA (each of 4 waves
// re-reads the whole 32KB B per tile x8 -> 512MB aggregate ~ 7.4us = MFMA's
// 7.3us; 64 FLOP/B vs the 68 FLOP/B LDS roofline). B is block-invariant and
// every wave needs ALL of it: 32KB/64 lanes = 512B/lane = 128 VGPR -> FITS.
// So: no LDS staging, no ds_reads, no barriers; each wave loads bf[4][4]
// (operand-major zt_perm, coalesced) once per block; the K-loop is 16
// register-only mfma_scale per tile. A-prefetch dropped to fit regs
// (bf 128 + acc 64 + af 32 + misc ~ 250). Plain __launch_bounds__(256):
// cap 256, natural alloc; 2 waves/SIMD, grid 512 = 2 blocks/CU as R8.
// Tripwires: VGPR_Count should be 200-256 (<=128 -> remat, theory untested;
// FETCH balloon -> spill). absmax must stay 0.0.
__global__ __launch_bounds__(256) void sim_fused(
    const unsigned char* __restrict__ za_f8, const unsigned char* __restrict__ zt_perm,
    const int* __restrict__ pid,
    float* __restrict__ s_row, float* __restrict__ s_col,
    float* __restrict__ posv)
{
    __shared__ int   pidc[128];
    __shared__ float colsum[128];

    const int bid   = blockIdx.x;
    const int cbb   = bid & 63;          // column block (fixed for this block)
    const int bgrp  = bid >> 6;          // 0..7 -> bands bgrp*8 .. bgrp*8+7
    const int col0g = cbb * 128;
    const int tid   = threadIdx.x, lane = tid & 63, wid = tid >> 6;
    const int l31   = lane & 31, h = lane >> 5;

    if (tid < 128) { pidc[tid] = pid[col0g + tid]; colsum[tid] = 0.f; }

    // ---- load ALL of B into registers: 16 operands x 32B/lane = 128 VGPR
    intx8 bf[4][4];
    {
        const unsigned char* gb = zt_perm + (size_t)cbb * 32768 + lane * 32;
        #pragma unroll
        for (int ks = 0; ks < 4; ks++)
            #pragma unroll
            for (int n = 0; n < 4; n++)
                bf[ks][n] = *(const intx8*)(gb + (ks * 4 + n) * 2048);
    }

    __syncthreads();   // pidc/colsum visible. ONLY barrier until the final flush.

    // col pids (tile-invariant)
    int pc[4];
    #pragma unroll
    for (int n = 0; n < 4; n++) pc[n] = pidc[n * 32 + l31];

    const int band0 = bgrp * 8;
    float colp4[4] = {0.f, 0.f, 0.f, 0.f};   // accumulates across ALL 8 tiles
    const int  target = (lane & 3) + 4 * ((lane >> 3) & 3);  // reg holding diag
    const bool ownl   = (h == ((lane >> 2) & 1));            // h matches row bit2

    #pragma unroll
    for (int i = 0; i < 8; i++) {
        const int band  = band0 + i;
        const int rbase = band * 128 + wid * 32;

        // A fragments for this tile (L2-hot; covered by other waves' MFMAs)
        intx8 afc[4];
        {
            const unsigned char* ga =
                za_f8 + (size_t)(rbase + l31) * DDIM + h * 32;
            #pragma unroll
            for (int ks = 0; ks < 4; ks++)
                afc[ks] = *(const intx8*)(ga + ks * 64);
        }

        // row pids for this tile (epilogue-only use)
        int prw[16];
        #pragma unroll
        for (int reg = 0; reg < 16; reg++)
            prw[reg] = pid[rbase + (reg & 3) + 8 * (reg >> 2) + 4 * h];

        // ---- GEMM: 16 register-only mfma_scale (zero memory ops)
        floatx16 acc[4];
        #pragma unroll
        for (int n = 0; n < 4; n++) acc[n] = (floatx16)0.0f;

        #pragma unroll
        for (int ks = 0; ks < 4; ks++)
            #pragma unroll
            for (int n = 0; n < 4; n++)
                acc[n] = __builtin_amdgcn_mfma_scale_f32_32x32x64_f8f6f4(
                    afc[ks], bf[ks][n], acc[n], 0, 0, 0,
                    0x7F7F7F7F, 0, 0x7F7F7F7F);

        // ---- epilogue (wave-local, no syncs)
        float rowp[16];
        #pragma unroll
        for (int r = 0; r < 16; r++) rowp[r] = 0.f;

        #pragma unroll
        for (int n = 0; n < 4; n++) {
            const int pcn = pc[n];
            #pragma unroll
            for (int reg = 0; reg < 16; reg++) {
                float e = __builtin_amdgcn_exp2f(fmaf(acc[n][reg], SC_L2E, -C2));
                e = (prw[reg] != pcn) ? e : 0.f;
                colp4[n] += e;
                rowp[reg] += e;
            }
            if (band == cbb && n == wid) {   // diagonal fixup (wave-uniform)
                float vd = 0.f;
                #pragma unroll
                for (int reg = 0; reg < 16; reg++)
                    vd = (reg == target) ? acc[n][reg] : vd;   // cndmask chain
                float ed = __builtin_amdgcn_exp2f(fmaf(vd, SC_L2E, -C2));
                ed = ownl ? ed : 0.f;
                colp4[n] += ed;
                #pragma unroll
                for (int reg = 0; reg < 16; reg++)
                    rowp[reg] += (reg == target) ? ed : 0.f;   // ed=0 if !ownl
                if (ownl) posv[band * 128 + wid * 32 + l31] = vd * SCALE;
            }
        }

        // row sums: split-tree reduce of rowp[16] over the 32-lane half
#define RED(bit, c)                                                        \
        _Pragma("unroll")                                                  \
        for (int _i = 0; _i < (c); _i++) {                                 \
            float _s = (lane & (bit)) ? rowp[_i] : rowp[_i + (c)];         \
            float _o = __shfl_xor(_s, (bit), 64);                          \
            rowp[_i] = ((lane & (bit)) ? rowp[_i + (c)] : rowp[_i]) + _o;  \
        }
        RED(1, 8) RED(2, 4) RED(4, 2) RED(8, 1)
#undef RED
        rowp[0] += __shfl_xor(rowp[0], 16, 64);
        if ((lane & 16) == 0) {
            const int reg = ((lane & 1) << 3) | ((lane & 2) << 1)
                          | ((lane & 4) >> 1) | ((lane & 8) >> 3);
            const int rl  = (reg & 3) + 8 * (reg >> 2) + 4 * h;
            atomicAdd(&s_row[rbase + rl], rowp[0]);
        }
    }

    // ---- col flush (once per block, after all 8 tiles)
    #pragma unroll
    for (int n = 0; n < 4; n++)
        colp4[n] += __shfl_xor(colp4[n], 32, 64);
    if (lane < 32) {
        #pragma unroll
        for (int n = 0; n < 4; n++)
            atomicAdd(&colsum[n * 32 + lane], colp4[n]);
    }
    __syncthreads();
    if (tid < 128) atomicAdd(&s_col[col0g + tid], colsum[tid]);
}

// ---------------------------------------------------------------- finalize (+ scalar write)
__global__ __launch_bounds__(256) void finalize_rows(
    const int* __restrict__ pid,
    const float* __restrict__ s_row, const float* __restrict__ s_col,
    const float* __restrict__ posv,
    float* __restrict__ total, int* __restrict__ flag, int* __restrict__ cnt,
    float* __restrict__ out)
{
    const int i = blockIdx.x * 256 + threadIdx.x;
    const float p = posv[i];
    const float c = (logf(s_row[i]) + C_OFF - p)
                  + (logf(s_col[i]) + C_OFF - p);

    float v = c;
    #pragma unroll
    for (int off = 32; off > 0; off >>= 1) v += __shfl_down(v, off, 64);
    if ((threadIdx.x & 63) == 0) atomicAdd(total, v);

    const unsigned long long m = __ballot(pid[i] != pid[0]);
    if (m != 0ull && (threadIdx.x & 63) == 0) atomicOr(flag, 1);

    __syncthreads();
    __threadfence();
    if (threadIdx.x == 0) {
        const int done = atomicAdd(cnt, 1);
        if (done == (int)gridDim.x - 1) {
            const float t = atomicAdd(total, 0.0f);
            const int   f = atomicOr(flag, 0);
            out[0] = f ? t / (2.0f * (float)BSZ) : 0.0f;
        }
    }
}

// ---------------------------------------------------------------- launcher
extern "C" void kernel_launch(void* const* d_in, const int* in_sizes, int n_in,
                              void* d_out, int out_size, void* d_ws, size_t ws_size,
                              hipStream_t stream)
{
    const float* za  = (const float*)d_in[0];
    const float* zt  = (const float*)d_in[1];
    const int*   pid = (const int*)d_in[2];
    float* out = (float*)d_out;

    // ws: za_f8 2MB | zt_perm 2MB | s_row[8192] s_col[8192] total flag cnt posv[8192]
    unsigned char* za_f8   = (unsigned char*)d_ws;
    unsigned char* zt_perm = za_f8 + (size_t)BSZ * DDIM;
    float*  s_row   = (float*)(zt_perm + (size_t)BSZ * DDIM);
    float*  s_col   = s_row + BSZ;
    float*  total   = s_col + BSZ;
    int*    flag    = (int*)(total + 1);
    int*    cnt     = flag + 1;
    float*  posv    = (float*)(cnt + 1);

    prep_kernel<<<dim3(2048), 256, 0, stream>>>(za, zt, za_f8, zt_perm, s_row);

    sim_fused<<<dim3(512), 256, 0, stream>>>(za_f8, zt_perm, pid,
                                             s_row, s_col, posv);

    finalize_rows<<<dim3(BSZ / 256), 256, 0, stream>>>(
        pid, s_row, s_col, posv, total, flag, cnt, out);
}

// Round 12
// 114.152 us; speedup vs baseline: 1.1517x; 1.0119x over previous
//
#include <hip/hip_runtime.h>
#include <math.h>

#define BSZ    8192
#define DDIM   256
#define SCALE  33.33333333333333f   // 1/0.03
#define C_OFF  34.0f                // fixed LSE offset: |sim*SCALE| <= 33.34
#define SC_L2E 48.08983470f         // SCALE * log2(e)
#define C2     49.05163139f         // C_OFF * log2(e)

typedef float floatx4  __attribute__((ext_vector_type(4)));
typedef float floatx16 __attribute__((ext_vector_type(16)));
typedef int   intx4    __attribute__((ext_vector_type(4)));
typedef int   intx8    __attribute__((ext_vector_type(8)));
typedef long long fp8x8;            // 8 x fp8 e4m3

// pack 8 fp32 -> 8 fp8 e4m3 (HW cvt; format matches the fp8 MFMA operand)
__device__ __forceinline__ fp8x8 cvt8_f8(const float* __restrict__ g)
{
    const float4 lo = *(const float4*)g;
    const float4 hi = *(const float4*)(g + 4);
    int a = __builtin_amdgcn_cvt_pk_fp8_f32(lo.x, lo.y, 0, false);
    a     = __builtin_amdgcn_cvt_pk_fp8_f32(lo.z, lo.w, a, true);
    int b = __builtin_amdgcn_cvt_pk_fp8_f32(hi.x, hi.y, 0, false);
    b     = __builtin_amdgcn_cvt_pk_fp8_f32(hi.z, hi.w, b, true);
    int2 r; r.x = a; r.y = b;
    return *(fp8x8*)&r;
}

// ---------------------------------------------------------------- prep (R11-identical)
// za_f8: row-major [8192][256] fp8.
// zt_perm operand-major layout:
//   byte(cb, o, lane, part) = cb*32768 + o*2048 + lane*32 + part*8, o = ks*4+n.
//   Lane l of operand (ks,n): col = cb*128 + n*32 + (l&31),
//   k = ks*64 + (l>>5)*32 + part*8 .. +8  (= HW B-operand layout for
//   mfma_scale_32x32x64; verified absmax 0.0 in R11).
__global__ __launch_bounds__(256) void prep_kernel(
    const float* __restrict__ za, const float* __restrict__ zt,
    unsigned char* __restrict__ za_f8, unsigned char* __restrict__ zt_perm,
    float* __restrict__ zbase)
{
    const int bid = blockIdx.x, tid = threadIdx.x;
    if (bid < 1024) {
        const int i = (bid * 256 + tid) * 8;
        *(fp8x8*)(za_f8 + i) = cvt8_f8(za + i);
        if (bid < 16) {
            const int z = bid * 1024 + tid * 4;
            *(float4*)&zbase[z] = (float4){0.f, 0.f, 0.f, 0.f};
            if (bid == 0 && tid == 0) {
                zbase[16384] = 0.f;          // total
                ((int*)zbase)[16385] = 0;    // flag
                ((int*)zbase)[16386] = 0;    // cnt
            }
        }
    } else {
        const int S    = (bid - 1024) * 256 + tid;   // global 8-B slot id
        const int cbb  = S >> 12;                    // col-block 0..63
        const int r    = S & 4095;                   // slot within cb (32KB)
        const int o    = r >> 8;                     // operand 0..15 (2KB each)
        const int w    = r & 255;                    // slot within operand
        const int ln   = w >> 2;                     // lane 0..63
        const int part = w & 3;                      // 8B part 0..3
        const int ks   = o >> 2, n = o & 3;
        const int col  = cbb * 128 + n * 32 + (ln & 31);
        const int k    = ks * 64 + (ln >> 5) * 32 + part * 8;
        const float* src = zt + (size_t)col * DDIM + k;
        *(fp8x8*)(zt_perm + (size_t)S * 8) = cvt8_f8(src);
    }
}

// ---------------------------------------------------------------- sim
// ROUND-12: R11 body + __launch_bounds__(256, 1).
// R11 post-mortem: plain launch_bounds(256) let the compiler's occupancy
// heuristic cap at 160 VGPR; bf(128)+acc(64) can't coexist -> bf was
// REMATERIALIZED from L2 every tile (no scratch: FETCH clean 9.7MB) ->
// the register-B theory went untested, sim 49.5us, occupancy 9.8%.
// Session launch-bounds model (measured): arg2=4 -> cap 64; arg2=2 -> ~128;
// none -> heuristic (160); arg2=1 -> full file (m08: ~512/wave usable).
// Budget: bf 128 + acc 64 + afc 32 + misc ~25 = ~250; 2 waves/SIMD x 250
// = 500 <= 512 pool -> grid 512 stays 2 blocks/CU resident.
// K-loop: 16 register-only mfma_scale per tile, B loaded ONCE per block,
// zero LDS pipe, zero K-loop barriers.
// Tripwires: VGPR_Count >= 224 (else remat again); FETCH ~9.7MB (else
// spill); absmax 0.0. Decision: clean but >= R8's ~35us -> register-B
// falsified, R8 is the keeper.
__global__ __launch_bounds__(256, 1) void sim_fused(
    const unsigned char* __restrict__ za_f8, const unsigned char* __restrict__ zt_perm,
    const int* __restrict__ pid,
    float* __restrict__ s_row, float* __restrict__ s_col,
    float* __restrict__ posv)
{
    __shared__ int   pidc[128];
    __shared__ float colsum[128];

    const int bid   = blockIdx.x;
    const int cbb   = bid & 63;          // column block (fixed for this block)
    const int bgrp  = bid >> 6;          // 0..7 -> bands bgrp*8 .. bgrp*8+7
    const int col0g = cbb * 128;
    const int tid   = threadIdx.x, lane = tid & 63, wid = tid >> 6;
    const int l31   = lane & 31, h = lane >> 5;

    if (tid < 128) { pidc[tid] = pid[col0g + tid]; colsum[tid] = 0.f; }

    // ---- load ALL of B into registers: 16 operands x 32B/lane = 128 VGPR
    intx8 bf[4][4];
    {
        const unsigned char* gb = zt_perm + (size_t)cbb * 32768 + lane * 32;
        #pragma unroll
        for (int ks = 0; ks < 4; ks++)
            #pragma unroll
            for (int n = 0; n < 4; n++)
                bf[ks][n] = *(const intx8*)(gb + (ks * 4 + n) * 2048);
    }

    __syncthreads();   // pidc/colsum visible. ONLY barrier until the final flush.

    // col pids (tile-invariant)
    int pc[4];
    #pragma unroll
    for (int n = 0; n < 4; n++) pc[n] = pidc[n * 32 + l31];

    const int band0 = bgrp * 8;
    float colp4[4] = {0.f, 0.f, 0.f, 0.f};   // accumulates across ALL 8 tiles
    const int  target = (lane & 3) + 4 * ((lane >> 3) & 3);  // reg holding diag
    const bool ownl   = (h == ((lane >> 2) & 1));            // h matches row bit2

    #pragma unroll
    for (int i = 0; i < 8; i++) {
        const int band  = band0 + i;
        const int rbase = band * 128 + wid * 32;

        // A fragments for this tile (L2-hot; covered by the co-wave's MFMAs)
        intx8 afc[4];
        {
            const unsigned char* ga =
                za_f8 + (size_t)(rbase + l31) * DDIM + h * 32;
            #pragma unroll
            for (int ks = 0; ks < 4; ks++)
                afc[ks] = *(const intx8*)(ga + ks * 64);
        }

        // row pids for this tile (epilogue-only use)
        int prw[16];
        #pragma unroll
        for (int reg = 0; reg < 16; reg++)
            prw[reg] = pid[rbase + (reg & 3) + 8 * (reg >> 2) + 4 * h];

        // ---- GEMM: 16 register-only mfma_scale (zero memory ops)
        floatx16 acc[4];
        #pragma unroll
        for (int n = 0; n < 4; n++) acc[n] = (floatx16)0.0f;

        #pragma unroll
        for (int ks = 0; ks < 4; ks++)
            #pragma unroll
            for (int n = 0; n < 4; n++)
                acc[n] = __builtin_amdgcn_mfma_scale_f32_32x32x64_f8f6f4(
                    afc[ks], bf[ks][n], acc[n], 0, 0, 0,
                    0x7F7F7F7F, 0, 0x7F7F7F7F);

        // ---- epilogue (wave-local, no syncs)
        float rowp[16];
        #pragma unroll
        for (int r = 0; r < 16; r++) rowp[r] = 0.f;

        #pragma unroll
        for (int n = 0; n < 4; n++) {
            const int pcn = pc[n];
            #pragma unroll
            for (int reg = 0; reg < 16; reg++) {
                float e = __builtin_amdgcn_exp2f(fmaf(acc[n][reg], SC_L2E, -C2));
                e = (prw[reg] != pcn) ? e : 0.f;
                colp4[n] += e;
                rowp[reg] += e;
            }
            if (band == cbb && n == wid) {   // diagonal fixup (wave-uniform)
                float vd = 0.f;
                #pragma unroll
                for (int reg = 0; reg < 16; reg++)
                    vd = (reg == target) ? acc[n][reg] : vd;   // cndmask chain
                float ed = __builtin_amdgcn_exp2f(fmaf(vd, SC_L2E, -C2));
                ed = ownl ? ed : 0.f;
                colp4[n] += ed;
                #pragma unroll
                for (int reg = 0; reg < 16; reg++)
                    rowp[reg] += (reg == target) ? ed : 0.f;   // ed=0 if !ownl
                if (ownl) posv[band * 128 + wid * 32 + l31] = vd * SCALE;
            }
        }

        // row sums: split-tree reduce of rowp[16] over the 32-lane half
#define RED(bit, c)                                                        \
        _Pragma("unroll")                                                  \
        for (int _i = 0; _i < (c); _i++) {                                 \
            float _s = (lane & (bit)) ? rowp[_i] : rowp[_i + (c)];         \
            float _o = __shfl_xor(_s, (bit), 64);                          \
            rowp[_i] = ((lane & (bit)) ? rowp[_i + (c)] : rowp[_i]) + _o;  \
        }
        RED(1, 8) RED(2, 4) RED(4, 2) RED(8, 1)
#undef RED
        rowp[0] += __shfl_xor(rowp[0], 16, 64);
        if ((lane & 16) == 0) {
            const int reg = ((lane & 1) << 3) | ((lane & 2) << 1)
                          | ((lane & 4) >> 1) | ((lane & 8) >> 3);
            const int rl  = (reg & 3) + 8 * (reg >> 2) + 4 * h;
            atomicAdd(&s_row[rbase + rl], rowp[0]);
        }
    }

    // ---- col flush (once per block, after all 8 tiles)
    #pragma unroll
    for (int n = 0; n < 4; n++)
        colp4[n] += __shfl_xor(colp4[n], 32, 64);
    if (lane < 32) {
        #pragma unroll
        for (int n = 0; n < 4; n++)
            atomicAdd(&colsum[n * 32 + lane], colp4[n]);
    }
    __syncthreads();
    if (tid < 128) atomicAdd(&s_col[col0g + tid], colsum[tid]);
}

// ---------------------------------------------------------------- finalize (+ scalar write)
__global__ __launch_bounds__(256) void finalize_rows(
    const int* __restrict__ pid,
    const float* __restrict__ s_row, const float* __restrict__ s_col,
    const float* __restrict__ posv,
    float* __restrict__ total, int* __restrict__ flag, int* __restrict__ cnt,
    float* __restrict__ out)
{
    const int i = blockIdx.x * 256 + threadIdx.x;
    const float p = posv[i];
    const float c = (logf(s_row[i]) + C_OFF - p)
                  + (logf(s_col[i]) + C_OFF - p);

    float v = c;
    #pragma unroll
    for (int off = 32; off > 0; off >>= 1) v += __shfl_down(v, off, 64);
    if ((threadIdx.x & 63) == 0) atomicAdd(total, v);

    const unsigned long long m = __ballot(pid[i] != pid[0]);
    if (m != 0ull && (threadIdx.x & 63) == 0) atomicOr(flag, 1);

    __syncthreads();
    __threadfence();
    if (threadIdx.x == 0) {
        const int done = atomicAdd(cnt, 1);
        if (done == (int)gridDim.x - 1) {
            const float t = atomicAdd(total, 0.0f);
            const int   f = atomicOr(flag, 0);
            out[0] = f ? t / (2.0f * (float)BSZ) : 0.0f;
        }
    }
}

// ---------------------------------------------------------------- launcher
extern "C" void kernel_launch(void* const* d_in, const int* in_sizes, int n_in,
                              void* d_out, int out_size, void* d_ws, size_t ws_size,
                              hipStream_t stream)
{
    const float* za  = (const float*)d_in[0];
    const float* zt  = (const float*)d_in[1];
    const int*   pid = (const int*)d_in[2];
    float* out = (float*)d_out;

    // ws: za_f8 2MB | zt_perm 2MB | s_row[8192] s_col[8192] total flag cnt posv[8192]
    unsigned char* za_f8   = (unsigned char*)d_ws;
    unsigned char* zt_perm = za_f8 + (size_t)BSZ * DDIM;
    float*  s_row   = (float*)(zt_perm + (size_t)BSZ * DDIM);
    float*  s_col   = s_row + BSZ;
    float*  total   = s_col + BSZ;
    int*    flag    = (int*)(total + 1);
    int*    cnt     = flag + 1;
    float*  posv    = (float*)(cnt + 1);

    prep_kernel<<<dim3(2048), 256, 0, stream>>>(za, zt, za_f8, zt_perm, s_row);

    sim_fused<<<dim3(512), 256, 0, stream>>>(za_f8, zt_perm, pid,
                                             s_row, s_col, posv);

    finalize_rows<<<dim3(BSZ / 256), 256, 0, stream>>>(
        pid, s_row, s_col, posv, total, flag, cnt, out);
}